// Round 4
// baseline (428.200 us; speedup 1.0000x reference)
//
#include <hip/hip_runtime.h>

#define NB 8
#define NN 2048
#define NF 256

typedef __attribute__((ext_vector_type(8))) short bf16x8;
typedef __attribute__((ext_vector_type(4))) float f32x4;

__device__ __forceinline__ unsigned short f2bf(float x) {
  union { float f; unsigned int i; } c; c.f = x;
  unsigned int r = c.i + 0x7FFFu + ((c.i >> 16) & 1u);
  return (unsigned short)(r >> 16);
}
// round-half-up bf16 (1 add + 1 shift) — hot convert paths
__device__ __forceinline__ unsigned short f2bf_fast(float x) {
  union { float f; unsigned int i; } c; c.f = x;
  return (unsigned short)((c.i + 0x8000u) >> 16);
}
__device__ __forceinline__ bf16x8 cvt8(float4 c0, float4 c1) {
  union { bf16x8 v8; unsigned short us[8]; } cu;
  cu.us[0] = f2bf_fast(c0.x); cu.us[1] = f2bf_fast(c0.y);
  cu.us[2] = f2bf_fast(c0.z); cu.us[3] = f2bf_fast(c0.w);
  cu.us[4] = f2bf_fast(c1.x); cu.us[5] = f2bf_fast(c1.y);
  cu.us[6] = f2bf_fast(c1.z); cu.us[7] = f2bf_fast(c1.w);
  return cu.v8;
}

// ---------------------------------------------------------------------------
// k_prep: WT[f][k] = bf16(W[k][f]);  u = W @ a1, v = W @ a2  (fp32)
// ---------------------------------------------------------------------------
__global__ __launch_bounds__(256) void k_prep(
    const float* __restrict__ W, const float* __restrict__ a,
    unsigned short* __restrict__ WT, float* __restrict__ u, float* __restrict__ v) {
  int t = threadIdx.x;
  if (blockIdx.x < 256) {
    int k = blockIdx.x;
    WT[t * 256 + k] = f2bf(W[k * 256 + t]);
  } else {
    float su = 0.f, sv = 0.f;
    for (int o = 0; o < 256; ++o) {
      float w = W[t * 256 + o];
      su += w * a[o];
      sv += w * a[256 + o];
    }
    u[t] = su; v[t] = sv;
  }
}

// ---------------------------------------------------------------------------
// k_wht: WhT[b][f][i] = sum_k W[k][f] * h[b][i][k]   (D[f][i] = W_T @ h^T)
// A = WT (bf16 row-major [f][k]) -> 16B contiguous a-frags
// B = h  (fp32 row-major [i][k]) -> 32B loads + in-register cvt to bf16
// grid 256: b(8) x fblk(4,64f) x iblk(8,256i); block 256 thr = 4 waves (2x2)
// ---------------------------------------------------------------------------
__global__ __launch_bounds__(256) void k_wht(
    const float* __restrict__ h, const unsigned short* __restrict__ WTr,
    unsigned short* __restrict__ WhT) {
  int bx = blockIdx.x;
  int b = bx >> 5;
  int t = bx & 31;
  int fBlk = (t >> 3) * 64;
  int iBlk = (t & 7) * 256;
  int wave = threadIdx.x >> 6, lane = threadIdx.x & 63;
  int fW = fBlk + (wave >> 1) * 32;
  int iW = iBlk + (wave & 1) * 128;
  int l15 = lane & 15, q8 = (lane >> 4) * 8;
  const float* hB = h + (size_t)b * NN * NF;

  f32x4 acc[2][8];
#pragma unroll
  for (int mt = 0; mt < 2; ++mt)
#pragma unroll
    for (int nt = 0; nt < 8; ++nt)
      acc[mt][nt] = (f32x4){0.f, 0.f, 0.f, 0.f};

  for (int k0 = 0; k0 < NF; k0 += 32) {
    int kk = k0 + q8;
    bf16x8 af[2], bfr[8];
#pragma unroll
    for (int mt = 0; mt < 2; ++mt) {
      int f = fW + mt * 16 + l15;
      af[mt] = *(const bf16x8*)(WTr + f * 256 + kk);
    }
#pragma unroll
    for (int nt = 0; nt < 8; ++nt) {
      int i = iW + nt * 16 + l15;
      const float* p = hB + (size_t)i * NF + kk;
      bfr[nt] = cvt8(*(const float4*)p, *(const float4*)(p + 4));
    }
#pragma unroll
    for (int mt = 0; mt < 2; ++mt)
#pragma unroll
      for (int nt = 0; nt < 8; ++nt)
        acc[mt][nt] = __builtin_amdgcn_mfma_f32_16x16x32_bf16(af[mt], bfr[nt], acc[mt][nt], 0, 0, 0);
  }

  unsigned short* WhTb = WhT + (size_t)b * NF * NN;
  int q4 = (lane >> 4) * 4;
#pragma unroll
  for (int mt = 0; mt < 2; ++mt)
#pragma unroll
    for (int nt = 0; nt < 8; ++nt)
#pragma unroll
      for (int r = 0; r < 4; ++r) {
        int f = fW + mt * 16 + q4 + r;
        int i = iW + nt * 16 + l15;
        WhTb[(size_t)f * NN + i] = f2bf(acc[mt][nt][r]);
      }
}

// ---------------------------------------------------------------------------
// k_proj: Wh1[row] = h[row,:] . u ; Wh2[row] = h[row,:] . v  (wave per row, fp32)
// ---------------------------------------------------------------------------
__global__ __launch_bounds__(256) void k_proj(
    const float* __restrict__ h, const float* __restrict__ u,
    const float* __restrict__ v, float* __restrict__ Wh1, float* __restrict__ Wh2) {
  int row = blockIdx.x * 4 + (threadIdx.x >> 6);
  int lane = threadIdx.x & 63;
  float4 hv = *(const float4*)(h + (size_t)row * NF + lane * 4);
  const float* up = u + lane * 4;
  const float* vp = v + lane * 4;
  float su = hv.x * up[0] + hv.y * up[1] + hv.z * up[2] + hv.w * up[3];
  float sv = hv.x * vp[0] + hv.y * vp[1] + hv.z * vp[2] + hv.w * vp[3];
#pragma unroll
  for (int off = 32; off >= 1; off >>= 1) {
    su += __shfl_xor(su, off);
    sv += __shfl_xor(sv, off);
  }
  if (lane == 0) { Wh1[row] = su; Wh2[row] = sv; }
}

// ---------------------------------------------------------------------------
// k_attn: one block per (b,i) row: masked leaky-relu scores, softmax, fp32 out
// thread t handles j = t*8 .. t*8+7 (contiguous -> vector loads/stores)
// ---------------------------------------------------------------------------
__global__ __launch_bounds__(256) void k_attn(
    const int* __restrict__ adj, const float* __restrict__ Wh1,
    const float* __restrict__ Wh2, float* __restrict__ att) {
  const float NEGBIG = -9.0e15f;
  int row = blockIdx.x;
  int b = row >> 11;
  int tid = threadIdx.x;
  int lane = tid & 63, wave = tid >> 6;
  const int* arow = adj + (size_t)row * NN;
  const float* w2 = Wh2 + ((size_t)b << 11);
  float w1 = Wh1[row];
  int j0 = tid * 8;

  int4 a0 = *(const int4*)(arow + j0);
  int4 a1 = *(const int4*)(arow + j0 + 4);
  float4 p0 = *(const float4*)(w2 + j0);
  float4 p1 = *(const float4*)(w2 + j0 + 4);

  float s[8];
  {
    float x;
    x = w1 + p0.x; x = x >= 0.f ? x : 0.2f * x; s[0] = (a0.x > 0) ? x : NEGBIG;
    x = w1 + p0.y; x = x >= 0.f ? x : 0.2f * x; s[1] = (a0.y > 0) ? x : NEGBIG;
    x = w1 + p0.z; x = x >= 0.f ? x : 0.2f * x; s[2] = (a0.z > 0) ? x : NEGBIG;
    x = w1 + p0.w; x = x >= 0.f ? x : 0.2f * x; s[3] = (a0.w > 0) ? x : NEGBIG;
    x = w1 + p1.x; x = x >= 0.f ? x : 0.2f * x; s[4] = (a1.x > 0) ? x : NEGBIG;
    x = w1 + p1.y; x = x >= 0.f ? x : 0.2f * x; s[5] = (a1.y > 0) ? x : NEGBIG;
    x = w1 + p1.z; x = x >= 0.f ? x : 0.2f * x; s[6] = (a1.z > 0) ? x : NEGBIG;
    x = w1 + p1.w; x = x >= 0.f ? x : 0.2f * x; s[7] = (a1.w > 0) ? x : NEGBIG;
  }

  float m = s[0];
#pragma unroll
  for (int k = 1; k < 8; ++k) m = fmaxf(m, s[k]);
#pragma unroll
  for (int off = 32; off >= 1; off >>= 1) m = fmaxf(m, __shfl_xor(m, off));

  __shared__ float redA[4], redB[4];
  if (lane == 0) redA[wave] = m;
  __syncthreads();
  m = fmaxf(fmaxf(redA[0], redA[1]), fmaxf(redA[2], redA[3]));

  float e[8];
  float sum = 0.f;
#pragma unroll
  for (int k = 0; k < 8; ++k) { e[k] = __expf(s[k] - m); sum += e[k]; }
#pragma unroll
  for (int off = 32; off >= 1; off >>= 1) sum += __shfl_xor(sum, off);
  if (lane == 0) redB[wave] = sum;
  __syncthreads();
  sum = (redB[0] + redB[1]) + (redB[2] + redB[3]);
  float inv = 1.0f / sum;

  float4 o0 = make_float4(e[0] * inv, e[1] * inv, e[2] * inv, e[3] * inv);
  float4 o1 = make_float4(e[4] * inv, e[5] * inv, e[6] * inv, e[7] * inv);
  float* orow = att + (size_t)row * NN + j0;
  *(float4*)(orow) = o0;
  *(float4*)(orow + 4) = o1;
}

// ---------------------------------------------------------------------------
// k_out: h_prime[b][i][f] = sum_j att[b][i][j] * WhT[b][f][j];
//        out = h + elu(h_prime)   (att fp32 -> bf16 in-register; out fp32)
// grid 256: b(8) x iblk(32,64i); block 4 waves (2i x 2f), wave 32i x 128f
// ---------------------------------------------------------------------------
__global__ __launch_bounds__(256) void k_out(
    const float* __restrict__ att, const unsigned short* __restrict__ WhT,
    const float* __restrict__ h, float* __restrict__ out) {
  int bx = blockIdx.x;
  int b = bx >> 5;
  int iBlk = (bx & 31) * 64;
  int wave = threadIdx.x >> 6, lane = threadIdx.x & 63;
  int iW = iBlk + (wave >> 1) * 32;
  int fW = (wave & 1) * 128;
  int l15 = lane & 15, q8 = (lane >> 4) * 8;
  const float* attB = att + (size_t)b * NN * NN;
  const unsigned short* WTb = WhT + (size_t)b * NF * NN;

  f32x4 acc[2][8];
#pragma unroll
  for (int mt = 0; mt < 2; ++mt)
#pragma unroll
    for (int nt = 0; nt < 8; ++nt)
      acc[mt][nt] = (f32x4){0.f, 0.f, 0.f, 0.f};

  for (int j0 = 0; j0 < NN; j0 += 32) {
    int kk = j0 + q8;
    bf16x8 af[2], bfr[8];
#pragma unroll
    for (int mt = 0; mt < 2; ++mt) {
      int i = iW + mt * 16 + l15;
      const float* p = attB + (size_t)i * NN + kk;
      af[mt] = cvt8(*(const float4*)p, *(const float4*)(p + 4));
    }
#pragma unroll
    for (int nt = 0; nt < 8; ++nt) {
      int f = fW + nt * 16 + l15;
      bfr[nt] = *(const bf16x8*)(WTb + (size_t)f * NN + kk);
    }
#pragma unroll
    for (int mt = 0; mt < 2; ++mt)
#pragma unroll
      for (int nt = 0; nt < 8; ++nt)
        acc[mt][nt] = __builtin_amdgcn_mfma_f32_16x16x32_bf16(af[mt], bfr[nt], acc[mt][nt], 0, 0, 0);
  }

  int q4 = (lane >> 4) * 4;
#pragma unroll
  for (int mt = 0; mt < 2; ++mt)
#pragma unroll
    for (int nt = 0; nt < 8; ++nt)
#pragma unroll
      for (int r = 0; r < 4; ++r) {
        int i = iW + mt * 16 + q4 + r;
        int f = fW + nt * 16 + l15;
        size_t idx = ((size_t)(b * NN + i)) * NF + f;
        float hp = acc[mt][nt][r];
        float el = hp > 0.f ? hp : expm1f(hp);
        out[idx] = h[idx] + el;
      }
}

// ---------------------------------------------------------------------------
extern "C" void kernel_launch(void* const* d_in, const int* in_sizes, int n_in,
                              void* d_out, int out_size, void* d_ws, size_t ws_size,
                              hipStream_t stream) {
  // identify inputs by element count (all four are distinct)
  const float* h = nullptr; const int* adj = nullptr;
  const float* W = nullptr; const float* a = nullptr;
  for (int i = 0; i < n_in; ++i) {
    int s = in_sizes[i];
    if (s == NB * NN * NF) h = (const float*)d_in[i];
    else if (s == NB * NN * NN) adj = (const int*)d_in[i];
    else if (s == NF * NF) W = (const float*)d_in[i];
    else if (s == 2 * NF) a = (const float*)d_in[i];
  }

  float* out = (float*)d_out;                              // [8,2048,256] fp32
  float* att = out + (size_t)NB * NN * NF;                 // [8,2048,2048] fp32

  // ws footprint: 8 MB + 128 KB + 2 KB + 128 KB ~= 8.26 MB (was 17 MB -> OOB)
  char* ws = (char*)d_ws;
  unsigned short* WhT = (unsigned short*)ws;               // 8 MB [8][256][2048] bf16
  unsigned short* WTr = (unsigned short*)(ws + 8388608);   // 128 KB [256][256] bf16
  float* u   = (float*)(ws + 8388608 + 131072);            // 1 KB
  float* v   = u + 256;                                    // 1 KB
  float* Wh1 = v + 256;                                    // 64 KB
  float* Wh2 = Wh1 + NB * NN;                              // 64 KB

  k_prep<<<257, 256, 0, stream>>>(W, a, WTr, u, v);
  k_wht<<<256, 256, 0, stream>>>(h, WTr, WhT);
  k_proj<<<NB * NN / 4, 256, 0, stream>>>(h, u, v, Wh1, Wh2);
  k_attn<<<NB * NN, 256, 0, stream>>>(adj, Wh1, Wh2, att);
  k_out<<<256, 256, 0, stream>>>(att, WhT, h, out);
}

// Round 5
// 419.722 us; speedup vs baseline: 1.0202x; 1.0202x over previous
//
#include <hip/hip_runtime.h>

#define NB 8
#define NN 2048
#define NF 256

typedef __attribute__((ext_vector_type(8))) short bf16x8;
typedef __attribute__((ext_vector_type(4))) float f32x4;

__device__ __forceinline__ unsigned short f2bf(float x) {
  union { float f; unsigned int i; } c; c.f = x;
  unsigned int r = c.i + 0x7FFFu + ((c.i >> 16) & 1u);
  return (unsigned short)(r >> 16);
}
// round-half-up bf16 (1 add + 1 shift) — hot convert paths
__device__ __forceinline__ unsigned short f2bf_fast(float x) {
  union { float f; unsigned int i; } c; c.f = x;
  return (unsigned short)((c.i + 0x8000u) >> 16);
}
__device__ __forceinline__ bf16x8 cvt8(float4 c0, float4 c1) {
  union { bf16x8 v8; unsigned short us[8]; } cu;
  cu.us[0] = f2bf_fast(c0.x); cu.us[1] = f2bf_fast(c0.y);
  cu.us[2] = f2bf_fast(c0.z); cu.us[3] = f2bf_fast(c0.w);
  cu.us[4] = f2bf_fast(c1.x); cu.us[5] = f2bf_fast(c1.y);
  cu.us[6] = f2bf_fast(c1.z); cu.us[7] = f2bf_fast(c1.w);
  return cu.v8;
}

// ---------------------------------------------------------------------------
// k_prep: WT[f][k] = bf16(W[k][f]);  u = W @ a1, v = W @ a2  (fp32)
// ---------------------------------------------------------------------------
__global__ __launch_bounds__(256) void k_prep(
    const float* __restrict__ W, const float* __restrict__ a,
    unsigned short* __restrict__ WT, float* __restrict__ u, float* __restrict__ v) {
  int t = threadIdx.x;
  if (blockIdx.x < 256) {
    int k = blockIdx.x;
    WT[t * 256 + k] = f2bf(W[k * 256 + t]);
  } else {
    float su = 0.f, sv = 0.f;
    for (int o = 0; o < 256; ++o) {
      float w = W[t * 256 + o];
      su += w * a[o];
      sv += w * a[256 + o];
    }
    u[t] = su; v[t] = sv;
  }
}

// ---------------------------------------------------------------------------
// k_wht: WhT[b][f][i] = sum_k W[k][f] * h[b][i][k]   (D[f][i] = W_T @ h^T)
// grid 512: b(8) x [fblk(4,64f) x iblk(16,128i)]; 4 waves (2f x 2i), wave 32f x 64i
// ---------------------------------------------------------------------------
__global__ __launch_bounds__(256) void k_wht(
    const float* __restrict__ h, const unsigned short* __restrict__ WTr,
    unsigned short* __restrict__ WhT) {
  int bx = blockIdx.x;
  int b = bx >> 6;
  int t = bx & 63;
  int fBlk = (t >> 4) * 64;
  int iBlk = (t & 15) * 128;
  int wave = threadIdx.x >> 6, lane = threadIdx.x & 63;
  int fW = fBlk + (wave >> 1) * 32;
  int iW = iBlk + (wave & 1) * 64;
  int l15 = lane & 15, q8 = (lane >> 4) * 8;
  const float* hB = h + (size_t)b * NN * NF;

  f32x4 acc[2][4];
#pragma unroll
  for (int mt = 0; mt < 2; ++mt)
#pragma unroll
    for (int nt = 0; nt < 4; ++nt)
      acc[mt][nt] = (f32x4){0.f, 0.f, 0.f, 0.f};

  for (int k0 = 0; k0 < NF; k0 += 32) {
    int kk = k0 + q8;
    bf16x8 af[2], bfr[4];
#pragma unroll
    for (int mt = 0; mt < 2; ++mt) {
      int f = fW + mt * 16 + l15;
      af[mt] = *(const bf16x8*)(WTr + f * 256 + kk);
    }
#pragma unroll
    for (int nt = 0; nt < 4; ++nt) {
      int i = iW + nt * 16 + l15;
      const float* p = hB + (size_t)i * NF + kk;
      bfr[nt] = cvt8(*(const float4*)p, *(const float4*)(p + 4));
    }
#pragma unroll
    for (int mt = 0; mt < 2; ++mt)
#pragma unroll
      for (int nt = 0; nt < 4; ++nt)
        acc[mt][nt] = __builtin_amdgcn_mfma_f32_16x16x32_bf16(af[mt], bfr[nt], acc[mt][nt], 0, 0, 0);
  }

  unsigned short* WhTb = WhT + (size_t)b * NF * NN;
  int q4 = (lane >> 4) * 4;
#pragma unroll
  for (int mt = 0; mt < 2; ++mt)
#pragma unroll
    for (int nt = 0; nt < 4; ++nt)
#pragma unroll
      for (int r = 0; r < 4; ++r) {
        int f = fW + mt * 16 + q4 + r;
        int i = iW + nt * 16 + l15;
        WhTb[(size_t)f * NN + i] = f2bf(acc[mt][nt][r]);
      }
}

// ---------------------------------------------------------------------------
// k_proj: Wh1[row] = h[row,:] . u ; Wh2[row] = h[row,:] . v  (wave per row, fp32)
// ---------------------------------------------------------------------------
__global__ __launch_bounds__(256) void k_proj(
    const float* __restrict__ h, const float* __restrict__ u,
    const float* __restrict__ v, float* __restrict__ Wh1, float* __restrict__ Wh2) {
  int row = blockIdx.x * 4 + (threadIdx.x >> 6);
  int lane = threadIdx.x & 63;
  float4 hv = *(const float4*)(h + (size_t)row * NF + lane * 4);
  const float* up = u + lane * 4;
  const float* vp = v + lane * 4;
  float su = hv.x * up[0] + hv.y * up[1] + hv.z * up[2] + hv.w * up[3];
  float sv = hv.x * vp[0] + hv.y * vp[1] + hv.z * vp[2] + hv.w * vp[3];
#pragma unroll
  for (int off = 32; off >= 1; off >>= 1) {
    su += __shfl_xor(su, off);
    sv += __shfl_xor(sv, off);
  }
  if (lane == 0) { Wh1[row] = su; Wh2[row] = sv; }
}

// ---------------------------------------------------------------------------
// k_attn: WAVE per row (no barriers, no LDS). 4 rows / 256-thr block.
// lane handles 32 j's: chunks c=0..7, j = c*256 + lane*4 (coalesced float4/int4)
// ---------------------------------------------------------------------------
__global__ __launch_bounds__(256) void k_attn(
    const int* __restrict__ adj, const float* __restrict__ Wh1,
    const float* __restrict__ Wh2, float* __restrict__ att) {
  const float NEGBIG = -9.0e15f;
  int wave = threadIdx.x >> 6, lane = threadIdx.x & 63;
  int row = blockIdx.x * 4 + wave;
  int b = row >> 11;
  const int* arow = adj + (size_t)row * NN;
  const float* w2 = Wh2 + ((size_t)b << 11);
  float w1 = Wh1[row];

  float s[32];
#pragma unroll
  for (int c = 0; c < 8; ++c) {
    int j = c * 256 + lane * 4;
    int4 av = *(const int4*)(arow + j);
    float4 pv = *(const float4*)(w2 + j);
    float x;
    x = w1 + pv.x; x = x >= 0.f ? x : 0.2f * x; s[c * 4 + 0] = (av.x > 0) ? x : NEGBIG;
    x = w1 + pv.y; x = x >= 0.f ? x : 0.2f * x; s[c * 4 + 1] = (av.y > 0) ? x : NEGBIG;
    x = w1 + pv.z; x = x >= 0.f ? x : 0.2f * x; s[c * 4 + 2] = (av.z > 0) ? x : NEGBIG;
    x = w1 + pv.w; x = x >= 0.f ? x : 0.2f * x; s[c * 4 + 3] = (av.w > 0) ? x : NEGBIG;
  }

  float m = s[0];
#pragma unroll
  for (int k = 1; k < 32; ++k) m = fmaxf(m, s[k]);
#pragma unroll
  for (int off = 32; off >= 1; off >>= 1) m = fmaxf(m, __shfl_xor(m, off));

  float sum = 0.f;
#pragma unroll
  for (int k = 0; k < 32; ++k) { s[k] = __expf(s[k] - m); sum += s[k]; }
#pragma unroll
  for (int off = 32; off >= 1; off >>= 1) sum += __shfl_xor(sum, off);
  float inv = 1.0f / sum;

  float* orow = att + (size_t)row * NN;
#pragma unroll
  for (int c = 0; c < 8; ++c) {
    int j = c * 256 + lane * 4;
    float4 o = make_float4(s[c * 4 + 0] * inv, s[c * 4 + 1] * inv,
                           s[c * 4 + 2] * inv, s[c * 4 + 3] * inv);
    *(float4*)(orow + j) = o;
  }
}

// ---------------------------------------------------------------------------
// k_out: h_prime[b][i][f] = sum_j att[b][i][j] * WhT[b][f][j];
//        out = h + elu(h_prime)
// grid 512: b(8) x iblk(64,32i); 4 waves split f: wave 32i x 64f, acc[2][4]
// ---------------------------------------------------------------------------
__global__ __launch_bounds__(256) void k_out(
    const float* __restrict__ att, const unsigned short* __restrict__ WhT,
    const float* __restrict__ h, float* __restrict__ out) {
  int bx = blockIdx.x;
  int b = bx >> 6;
  int iW = (bx & 63) * 32;
  int wave = threadIdx.x >> 6, lane = threadIdx.x & 63;
  int fW = wave * 64;
  int l15 = lane & 15, q8 = (lane >> 4) * 8;
  const float* attB = att + (size_t)b * NN * NN;
  const unsigned short* WTb = WhT + (size_t)b * NF * NN;

  f32x4 acc[2][4];
#pragma unroll
  for (int mt = 0; mt < 2; ++mt)
#pragma unroll
    for (int nt = 0; nt < 4; ++nt)
      acc[mt][nt] = (f32x4){0.f, 0.f, 0.f, 0.f};

  for (int j0 = 0; j0 < NN; j0 += 32) {
    int kk = j0 + q8;
    bf16x8 af[2], bfr[4];
#pragma unroll
    for (int mt = 0; mt < 2; ++mt) {
      int i = iW + mt * 16 + l15;
      const float* p = attB + (size_t)i * NN + kk;
      af[mt] = cvt8(*(const float4*)p, *(const float4*)(p + 4));
    }
#pragma unroll
    for (int nt = 0; nt < 4; ++nt) {
      int f = fW + nt * 16 + l15;
      bfr[nt] = *(const bf16x8*)(WTb + (size_t)f * NN + kk);
    }
#pragma unroll
    for (int mt = 0; mt < 2; ++mt)
#pragma unroll
      for (int nt = 0; nt < 4; ++nt)
        acc[mt][nt] = __builtin_amdgcn_mfma_f32_16x16x32_bf16(af[mt], bfr[nt], acc[mt][nt], 0, 0, 0);
  }

  int q4 = (lane >> 4) * 4;
#pragma unroll
  for (int mt = 0; mt < 2; ++mt)
#pragma unroll
    for (int nt = 0; nt < 4; ++nt)
#pragma unroll
      for (int r = 0; r < 4; ++r) {
        int i = iW + mt * 16 + q4 + r;
        int f = fW + nt * 16 + l15;
        size_t idx = ((size_t)(b * NN + i)) * NF + f;
        float hp = acc[mt][nt][r];
        float el = hp > 0.f ? hp : expm1f(hp);
        out[idx] = h[idx] + el;
      }
}

// ---------------------------------------------------------------------------
extern "C" void kernel_launch(void* const* d_in, const int* in_sizes, int n_in,
                              void* d_out, int out_size, void* d_ws, size_t ws_size,
                              hipStream_t stream) {
  // identify inputs by element count (all four are distinct)
  const float* h = nullptr; const int* adj = nullptr;
  const float* W = nullptr; const float* a = nullptr;
  for (int i = 0; i < n_in; ++i) {
    int s = in_sizes[i];
    if (s == NB * NN * NF) h = (const float*)d_in[i];
    else if (s == NB * NN * NN) adj = (const int*)d_in[i];
    else if (s == NF * NF) W = (const float*)d_in[i];
    else if (s == 2 * NF) a = (const float*)d_in[i];
  }

  float* out = (float*)d_out;                              // [8,2048,256] fp32
  float* att = out + (size_t)NB * NN * NF;                 // [8,2048,2048] fp32

  // ws footprint ~8.26 MB (proven safe)
  char* ws = (char*)d_ws;
  unsigned short* WhT = (unsigned short*)ws;               // 8 MB [8][256][2048] bf16
  unsigned short* WTr = (unsigned short*)(ws + 8388608);   // 128 KB [256][256] bf16
  float* u   = (float*)(ws + 8388608 + 131072);            // 1 KB
  float* v   = u + 256;                                    // 1 KB
  float* Wh1 = v + 256;                                    // 64 KB
  float* Wh2 = Wh1 + NB * NN;                              // 64 KB

  k_prep<<<257, 256, 0, stream>>>(W, a, WTr, u, v);
  k_wht<<<512, 256, 0, stream>>>(h, WTr, WhT);
  k_proj<<<NB * NN / 4, 256, 0, stream>>>(h, u, v, Wh1, Wh2);
  k_attn<<<NB * NN / 4, 256, 0, stream>>>(adj, Wh1, Wh2, att);
  k_out<<<512, 256, 0, stream>>>(att, WhT, h, out);
}

// Round 6
// 400.634 us; speedup vs baseline: 1.0688x; 1.0476x over previous
//
#include <hip/hip_runtime.h>

#define NB 8
#define NN 2048
#define NF 256

typedef __attribute__((ext_vector_type(8))) short bf16x8;
typedef __attribute__((ext_vector_type(4))) float f32x4;

__device__ __forceinline__ unsigned short f2bf(float x) {
  union { float f; unsigned int i; } c; c.f = x;
  unsigned int r = c.i + 0x7FFFu + ((c.i >> 16) & 1u);
  return (unsigned short)(r >> 16);
}
// round-half-up bf16 (1 add + 1 shift) — hot convert paths
__device__ __forceinline__ unsigned short f2bf_fast(float x) {
  union { float f; unsigned int i; } c; c.f = x;
  return (unsigned short)((c.i + 0x8000u) >> 16);
}
__device__ __forceinline__ bf16x8 cvt8(float4 c0, float4 c1) {
  union { bf16x8 v8; unsigned short us[8]; } cu;
  cu.us[0] = f2bf_fast(c0.x); cu.us[1] = f2bf_fast(c0.y);
  cu.us[2] = f2bf_fast(c0.z); cu.us[3] = f2bf_fast(c0.w);
  cu.us[4] = f2bf_fast(c1.x); cu.us[5] = f2bf_fast(c1.y);
  cu.us[6] = f2bf_fast(c1.z); cu.us[7] = f2bf_fast(c1.w);
  return cu.v8;
}

// ---------------------------------------------------------------------------
// k_prep: WT[f][k] = bf16(W[k][f]);  u = W @ a1, v = W @ a2  (fp32)
// ---------------------------------------------------------------------------
__global__ __launch_bounds__(256) void k_prep(
    const float* __restrict__ W, const float* __restrict__ a,
    unsigned short* __restrict__ WT, float* __restrict__ u, float* __restrict__ v) {
  int t = threadIdx.x;
  if (blockIdx.x < 256) {
    int k = blockIdx.x;
    WT[t * 256 + k] = f2bf(W[k * 256 + t]);
  } else {
    float su = 0.f, sv = 0.f;
    for (int o = 0; o < 256; ++o) {
      float w = W[t * 256 + o];
      su += w * a[o];
      sv += w * a[256 + o];
    }
    u[t] = su; v[t] = sv;
  }
}

// ---------------------------------------------------------------------------
// k_wht: WhT[b][f][i] = sum_k W[k][f] * h[b][i][k]
// grid 512: b(8) x [fblk(4,64f) x iblk(16,128i)]; 4 waves (2f x 2i), wave 32f x 64i
// ---------------------------------------------------------------------------
__global__ __launch_bounds__(256) void k_wht(
    const float* __restrict__ h, const unsigned short* __restrict__ WTr,
    unsigned short* __restrict__ WhT) {
  int bx = blockIdx.x;
  int b = bx >> 6;
  int t = bx & 63;
  int fBlk = (t >> 4) * 64;
  int iBlk = (t & 15) * 128;
  int wave = threadIdx.x >> 6, lane = threadIdx.x & 63;
  int fW = fBlk + (wave >> 1) * 32;
  int iW = iBlk + (wave & 1) * 64;
  int l15 = lane & 15, q8 = (lane >> 4) * 8;
  const float* hB = h + (size_t)b * NN * NF;

  f32x4 acc[2][4];
#pragma unroll
  for (int mt = 0; mt < 2; ++mt)
#pragma unroll
    for (int nt = 0; nt < 4; ++nt)
      acc[mt][nt] = (f32x4){0.f, 0.f, 0.f, 0.f};

  for (int k0 = 0; k0 < NF; k0 += 32) {
    int kk = k0 + q8;
    bf16x8 af[2], bfr[4];
#pragma unroll
    for (int mt = 0; mt < 2; ++mt) {
      int f = fW + mt * 16 + l15;
      af[mt] = *(const bf16x8*)(WTr + f * 256 + kk);
    }
#pragma unroll
    for (int nt = 0; nt < 4; ++nt) {
      int i = iW + nt * 16 + l15;
      const float* p = hB + (size_t)i * NF + kk;
      bfr[nt] = cvt8(*(const float4*)p, *(const float4*)(p + 4));
    }
#pragma unroll
    for (int mt = 0; mt < 2; ++mt)
#pragma unroll
      for (int nt = 0; nt < 4; ++nt)
        acc[mt][nt] = __builtin_amdgcn_mfma_f32_16x16x32_bf16(af[mt], bfr[nt], acc[mt][nt], 0, 0, 0);
  }

  unsigned short* WhTb = WhT + (size_t)b * NF * NN;
  int q4 = (lane >> 4) * 4;
#pragma unroll
  for (int mt = 0; mt < 2; ++mt)
#pragma unroll
    for (int nt = 0; nt < 4; ++nt)
#pragma unroll
      for (int r = 0; r < 4; ++r) {
        int f = fW + mt * 16 + q4 + r;
        int i = iW + nt * 16 + l15;
        WhTb[(size_t)f * NN + i] = f2bf(acc[mt][nt][r]);
      }
}

// ---------------------------------------------------------------------------
// k_proj: Wh1[row] = h[row,:] . u ; Wh2[row] = h[row,:] . v  (wave per row, fp32)
// ---------------------------------------------------------------------------
__global__ __launch_bounds__(256) void k_proj(
    const float* __restrict__ h, const float* __restrict__ u,
    const float* __restrict__ v, float* __restrict__ Wh1, float* __restrict__ Wh2) {
  int row = blockIdx.x * 4 + (threadIdx.x >> 6);
  int lane = threadIdx.x & 63;
  float4 hv = *(const float4*)(h + (size_t)row * NF + lane * 4);
  const float* up = u + lane * 4;
  const float* vp = v + lane * 4;
  float su = hv.x * up[0] + hv.y * up[1] + hv.z * up[2] + hv.w * up[3];
  float sv = hv.x * vp[0] + hv.y * vp[1] + hv.z * vp[2] + hv.w * vp[3];
#pragma unroll
  for (int off = 32; off >= 1; off >>= 1) {
    su += __shfl_xor(su, off);
    sv += __shfl_xor(sv, off);
  }
  if (lane == 0) { Wh1[row] = su; Wh2[row] = sv; }
}

// ---------------------------------------------------------------------------
// k_fuse: softmax (16 rows) + att@WhT + h+elu epilogue, one block per row-tile.
// Phase 1: wave handles 4 rows; 64 loads in flight; writes fp32 att to global
//          and normalized bf16 att into XOR-swizzled LDS (swz = row*8).
// Phase 2: GEMM 16i x 256f x 2048j; A from LDS ds_read_b128 (2-way = free),
//          B = WhT[b][f][j] 16B frags (L2-resident); fused out = h + elu.
// grid 1024: b(8) x itile(128,16i); LDS 64 KB -> 2 blocks/CU.
// ---------------------------------------------------------------------------
__global__ __launch_bounds__(256, 2) void k_fuse(
    const int* __restrict__ adj, const float* __restrict__ Wh1,
    const float* __restrict__ Wh2, const unsigned short* __restrict__ WhT,
    const float* __restrict__ h, float* __restrict__ att, float* __restrict__ out) {
  __shared__ unsigned short satt[16 * 2048];  // 64 KB, XOR-swizzled rows
  const float NEGBIG = -9.0e15f;
  int bx = blockIdx.x;
  int b = bx >> 7;
  int i0 = (bx & 127) * 16;
  int wave = threadIdx.x >> 6, lane = threadIdx.x & 63;
  const float* w2 = Wh2 + ((size_t)b << 11);

  // ---------------- phase 1: masked-softmax for rows i0+wave*4 .. +3 -------
  float s[4][32];
  int rowbase = b * NN + i0 + wave * 4;
#pragma unroll
  for (int rr = 0; rr < 4; ++rr) {
    const int* arow = adj + (size_t)(rowbase + rr) * NN;
    float w1 = Wh1[rowbase + rr];
#pragma unroll
    for (int c = 0; c < 8; ++c) {
      int j = c * 256 + lane * 4;
      int4 av = *(const int4*)(arow + j);
      float4 pv = *(const float4*)(w2 + j);
      float x;
      x = w1 + pv.x; x = x >= 0.f ? x : 0.2f * x; s[rr][c*4+0] = (av.x > 0) ? x : NEGBIG;
      x = w1 + pv.y; x = x >= 0.f ? x : 0.2f * x; s[rr][c*4+1] = (av.y > 0) ? x : NEGBIG;
      x = w1 + pv.z; x = x >= 0.f ? x : 0.2f * x; s[rr][c*4+2] = (av.z > 0) ? x : NEGBIG;
      x = w1 + pv.w; x = x >= 0.f ? x : 0.2f * x; s[rr][c*4+3] = (av.w > 0) ? x : NEGBIG;
    }
  }

  float inv[4];
#pragma unroll
  for (int rr = 0; rr < 4; ++rr) {
    float m = s[rr][0];
#pragma unroll
    for (int k = 1; k < 32; ++k) m = fmaxf(m, s[rr][k]);
#pragma unroll
    for (int off = 32; off >= 1; off >>= 1) m = fmaxf(m, __shfl_xor(m, off));
    float sum = 0.f;
#pragma unroll
    for (int k = 0; k < 32; ++k) { s[rr][k] = __expf(s[rr][k] - m); sum += s[rr][k]; }
#pragma unroll
    for (int off = 32; off >= 1; off >>= 1) sum += __shfl_xor(sum, off);
    inv[rr] = 1.0f / sum;
  }

#pragma unroll
  for (int rr = 0; rr < 4; ++rr) {
    int row_local = wave * 4 + rr;
    int swz = row_local * 8;
    float* orow = att + (size_t)(rowbase + rr) * NN;
    unsigned short* srow = satt + row_local * 2048;
    float iv = inv[rr];
#pragma unroll
    for (int c = 0; c < 8; ++c) {
      int j = c * 256 + lane * 4;
      float a0 = s[rr][c*4+0] * iv, a1 = s[rr][c*4+1] * iv;
      float a2 = s[rr][c*4+2] * iv, a3 = s[rr][c*4+3] * iv;
      *(float4*)(orow + j) = make_float4(a0, a1, a2, a3);
      // LDS: 4 bf16 (8B) at swizzled offset; groups of 8 permuted by swz
      int e = ((j & ~7) ^ swz) + (j & 7);
      union { short4 v4; unsigned short us[4]; } pk;
      pk.us[0] = f2bf_fast(a0); pk.us[1] = f2bf_fast(a1);
      pk.us[2] = f2bf_fast(a2); pk.us[3] = f2bf_fast(a3);
      *(short4*)(srow + e) = pk.v4;
    }
  }

  __syncthreads();

  // ---------------- phase 2: h_prime = att @ Wh, out = h + elu -------------
  int fW = wave * 64;
  int l15 = lane & 15, q8 = (lane >> 4) * 8;
  const unsigned short* WTb = WhT + (size_t)b * NF * NN;
  const unsigned short* aRow = satt + l15 * 2048;
  int swzA = l15 * 8;

  f32x4 acc[4];
#pragma unroll
  for (int nt = 0; nt < 4; ++nt) acc[nt] = (f32x4){0.f, 0.f, 0.f, 0.f};

  for (int kk = 0; kk < NN; kk += 32) {
    bf16x8 afr = *(const bf16x8*)(aRow + (((kk + q8) ^ swzA)));
    bf16x8 bfr[4];
#pragma unroll
    for (int nt = 0; nt < 4; ++nt) {
      int f = fW + nt * 16 + l15;
      bfr[nt] = *(const bf16x8*)(WTb + (size_t)f * NN + kk + q8);
    }
#pragma unroll
    for (int nt = 0; nt < 4; ++nt)
      acc[nt] = __builtin_amdgcn_mfma_f32_16x16x32_bf16(afr, bfr[nt], acc[nt], 0, 0, 0);
  }

  int q4 = (lane >> 4) * 4;
#pragma unroll
  for (int nt = 0; nt < 4; ++nt)
#pragma unroll
    for (int r = 0; r < 4; ++r) {
      int i = i0 + q4 + r;
      int f = fW + nt * 16 + l15;
      size_t idx = ((size_t)(b * NN + i)) * NF + f;
      float hp = acc[nt][r];
      float el = hp > 0.f ? hp : expm1f(hp);
      out[idx] = h[idx] + el;
    }
}

// ---------------------------------------------------------------------------
extern "C" void kernel_launch(void* const* d_in, const int* in_sizes, int n_in,
                              void* d_out, int out_size, void* d_ws, size_t ws_size,
                              hipStream_t stream) {
  // identify inputs by element count (all four are distinct)
  const float* h = nullptr; const int* adj = nullptr;
  const float* W = nullptr; const float* a = nullptr;
  for (int i = 0; i < n_in; ++i) {
    int s = in_sizes[i];
    if (s == NB * NN * NF) h = (const float*)d_in[i];
    else if (s == NB * NN * NN) adj = (const int*)d_in[i];
    else if (s == NF * NF) W = (const float*)d_in[i];
    else if (s == 2 * NF) a = (const float*)d_in[i];
  }

  float* out = (float*)d_out;                              // [8,2048,256] fp32
  float* att = out + (size_t)NB * NN * NF;                 // [8,2048,2048] fp32

  // ws footprint ~8.26 MB (proven safe)
  char* ws = (char*)d_ws;
  unsigned short* WhT = (unsigned short*)ws;               // 8 MB [8][256][2048] bf16
  unsigned short* WTr = (unsigned short*)(ws + 8388608);   // 128 KB [256][256] bf16
  float* u   = (float*)(ws + 8388608 + 131072);            // 1 KB
  float* v   = u + 256;                                    // 1 KB
  float* Wh1 = v + 256;                                    // 64 KB
  float* Wh2 = Wh1 + NB * NN;                              // 64 KB

  k_prep<<<257, 256, 0, stream>>>(W, a, WTr, u, v);
  k_wht<<<512, 256, 0, stream>>>(h, WTr, WhT);
  k_proj<<<NB * NN / 4, 256, 0, stream>>>(h, u, v, Wh1, Wh2);
  k_fuse<<<NB * 128, 256, 0, stream>>>(adj, Wh1, Wh2, WhT, h, att, out);
}